// Round 2
// baseline (337.862 us; speedup 1.0000x reference)
//
#include <hip/hip_runtime.h>

#define SEQ    512
#define BATCHN 32768
#define NC     16      // chunks
#define CL     32      // steps per chunk (NC*CL == SEQ)
#define SMINF  0.01f
#define SMAXF  36500.0f

// ---------------------------------------------------------------------------
// Pass A: compress ratings (2 bits each) so later passes never re-read the
// 134 MB input. Thread (c,b) packs its chunk's 32 ratings into one uint64.
// ---------------------------------------------------------------------------
__global__ __launch_bounds__(256) void k_compress(const float* __restrict__ in,
                                                  unsigned long long* __restrict__ rat) {
    const int tid = blockIdx.x * 256 + threadIdx.x;   // tid = c*BATCHN + b
    const int c = tid >> 15;
    const int b = tid & (BATCHN - 1);
    const float* p = in + (((size_t)(c * CL) * BATCHN + b) * 2 + 1);
    float rr[CL];
#pragma unroll
    for (int t = 0; t < CL; ++t) rr[t] = p[(size_t)t * (BATCHN * 2)];
    unsigned long long wd = 0ull;
#pragma unroll
    for (int t = 0; t < CL; ++t)
        wd |= (unsigned long long)((unsigned)rr[t]) << (2 * t);
    rat[tid] = wd;
}

// ---------------------------------------------------------------------------
// Pass B: per-chain serial scan of the ef and reps recurrences (independent of
// ivl). Reads only compressed ratings (128 B/thread). Stores state at every
// chunk boundary (index NC = end-of-sequence state).
// ---------------------------------------------------------------------------
__global__ __launch_bounds__(256) void k_efreps(const unsigned long long* __restrict__ rat,
                                                const float* __restrict__ wp,
                                                float* __restrict__ efS,
                                                float* __restrict__ repsS) {
    const int b = blockIdx.x * 256 + threadIdx.x;
    const float w2 = wp[2], w3 = wp[3], w4 = wp[4], w5 = wp[5];
    unsigned long long wd[NC];
#pragma unroll
    for (int c = 0; c < NC; ++c) wd[c] = rat[c * BATCHN + b];
    float ef = w2;
    int reps = 0;
#pragma unroll 1
    for (int c = 0; c < NC; ++c) {
        efS[c * BATCHN + b]   = ef;
        repsS[c * BATCHN + b] = (float)reps;
        const unsigned long long w = wd[c];
#pragma unroll
        for (int t = 0; t < CL; ++t) {
            const unsigned r = (unsigned)(w >> (2 * t)) & 3u;
            reps = (r > 1u) ? (reps + 1) : 1;
            const float q = (float)(r + 1u);
            const float d = q - w4;
            ef = fminf(fmaxf(ef - w3 * (d * d) + w5, 1.3f), 10.0f);
        }
    }
    efS[NC * BATCHN + b]   = ef;
    repsS[NC * BATCHN + b] = (float)reps;
}

// ---------------------------------------------------------------------------
// Pass C: replay each chunk with known (ef,reps) start state; writes all
// outputs. ivl is unknown only until the chunk's first reset (new_reps in
// {1,2}); on that symbolic prefix we emit the running ef-product prodP_t
// (valid because every multiplier >= 1.3 > 1, so per-step clips commute with
// the product) for pass D to scale by ivl_in. Also emits the chunk's ivl
// transfer: concrete end value, or full product if no reset occurred.
// ---------------------------------------------------------------------------
__global__ __launch_bounds__(256) void k_replay(const unsigned long long* __restrict__ rat,
                                                const float* __restrict__ wp,
                                                const float* __restrict__ efS,
                                                const float* __restrict__ repsS,
                                                float* __restrict__ ivlV,
                                                int* __restrict__ prefL,
                                                float* __restrict__ out) {
    const int tid = blockIdx.x * 256 + threadIdx.x;
    const int c = tid >> 15;
    const int b = tid & (BATCHN - 1);
    const unsigned long long wd = rat[tid];
    float ef  = efS[c * BATCHN + b];
    int  reps = (int)repsS[c * BATCHN + b];
    const float w0 = wp[0], w1 = wp[1], w3 = wp[3], w4 = wp[4], w5 = wp[5];
    const float civ0 = fminf(fmaxf(w0, SMINF), SMAXF);
    const float civ1 = fminf(fmaxf(w1, SMINF), SMAXF);
    bool  sym = true;        // ivl still proportional to unknown ivl_in
    float ivl = 0.0f, p = 1.0f;
    int   plen = 0;
    float* o = out + (((size_t)(c * CL) * BATCHN + b) * 3);
#pragma unroll
    for (int t = 0; t < CL; ++t) {
        const unsigned r = (unsigned)(wd >> (2 * t)) & 3u;
        reps = (r > 1u) ? (reps + 1) : 1;
        if (reps == 1)      { ivl = civ0; sym = false; }            // reset
        else if (reps == 2) { ivl = civ1; sym = false; }            // reset
        else if (sym)       { p *= ef; ++plen; }                    // symbolic multiply
        else                { ivl = fminf(fmaxf(ivl * ef, SMINF), SMAXF); }
        const float outv = sym ? p : ivl;   // prefix slots hold prodP_t (patched in D)
        const float q = (float)(r + 1u);
        const float d = q - w4;
        ef = fminf(fmaxf(ef - w3 * (d * d) + w5, 1.3f), 10.0f);    // new ef (written)
        o[0] = outv;
        o[1] = ef;
        o[2] = (float)reps;
        o += (size_t)BATCHN * 3;
    }
    ivlV[tid]  = sym ? p : ivl;   // transfer: product (sym) or concrete end
    prefL[tid] = plen;
}

// ---------------------------------------------------------------------------
// Pass D: per-chain compose of chunk ivl-transfers (16 steps), patching each
// chunk's symbolic prefix in place, then write final_state.
// ---------------------------------------------------------------------------
__global__ __launch_bounds__(256) void k_compose(const float* __restrict__ efS,
                                                 const float* __restrict__ repsS,
                                                 const float* __restrict__ ivlV,
                                                 const int* __restrict__ prefL,
                                                 float* __restrict__ out) {
    const int b = blockIdx.x * 256 + threadIdx.x;
    float pv[NC]; int pl[NC];
#pragma unroll
    for (int c = 0; c < NC; ++c) {
        pv[c] = ivlV[c * BATCHN + b];
        pl[c] = prefL[c * BATCHN + b];
    }
    float ivl = 0.0f;
#pragma unroll 1
    for (int c = 0; c < NC; ++c) {
        const int n = pl[c];
        if (n > 0) {                       // patch symbolic prefix (rare, short)
            const float istart = ivl;
            float* o = out + (((size_t)(c * CL) * BATCHN + b) * 3);
            for (int t = 0; t < n; ++t) {
                o[0] = fminf(istart * o[0], SMAXF);   // lower clip can't bind (>= SMIN*1.3)
                o += (size_t)BATCHN * 3;
            }
        }
        ivl = (n == CL) ? fminf(ivl * pv[c], SMAXF) : pv[c];
    }
    float* f = out + (size_t)SEQ * BATCHN * 3 + (size_t)b * 3;
    f[0] = ivl;
    f[1] = efS[NC * BATCHN + b];
    f[2] = repsS[NC * BATCHN + b];
}

extern "C" void kernel_launch(void* const* d_in, const int* in_sizes, int n_in,
                              void* d_out, int out_size, void* d_ws, size_t ws_size,
                              hipStream_t stream) {
    const float* in = (const float*)d_in[0];
    const float* w  = (const float*)d_in[1];
    float* out      = (float*)d_out;
    char* ws        = (char*)d_ws;

    // ws layout (12.85 MB total):
    unsigned long long* rat = (unsigned long long*)(ws);            //  4,194,304 B
    float* efS   = (float*)(ws + 4194304);                          //  2,228,224 B
    float* repsS = (float*)(ws + 6422528);                          //  2,228,224 B
    float* ivlV  = (float*)(ws + 8650752);                          //  2,097,152 B
    int*   prefL = (int*)  (ws + 10747904);                         //  2,097,152 B

    k_compress<<<NC * BATCHN / 256, 256, 0, stream>>>(in, rat);
    k_efreps  <<<BATCHN / 256,      256, 0, stream>>>(rat, w, efS, repsS);
    k_replay  <<<NC * BATCHN / 256, 256, 0, stream>>>(rat, w, efS, repsS, ivlV, prefL, out);
    k_compose <<<BATCHN / 256,      256, 0, stream>>>(efS, repsS, ivlV, prefL, out);
}